// Round 10
// baseline (68.843 us; speedup 1.0000x reference)
//
#include <hip/hip_runtime.h>
#include <math.h>

#define NROWS 100000
#define CCOLS 1024
#define GRID  1024
#define BLOCK 256
#define WPB   (BLOCK / 64)   // waves per block

typedef float f32x4 __attribute__((ext_vector_type(4)));  // native vector for nontemporal builtin

// One wave per ROW-QUAD, grid-stride. 16 nt-loads in flight per iteration; the
// four 64-lane reduce chains interleave (independent), quartering the per-row
// pipeline bubble. Epilogue stays lane0-serial (measured cheap).
__global__ __launch_bounds__(BLOCK) void bp_main(
    const float* __restrict__ cs,        // [N, C] class_scores
    const float* __restrict__ xywh,      // [N, 4]
    const float* __restrict__ z,         // [N]
    const float* __restrict__ r,         // [N]
    const int*   __restrict__ nearest,   // [N]
    const int*   __restrict__ gt_lbl,    // [M]
    const float* __restrict__ gt_xywh,   // [M, 4]
    float* __restrict__ partials,        // [3 * GRID]
    int n)
{
    const int lane  = threadIdx.x & 63;
    const int wave  = threadIdx.x >> 6;
    const int gwave = blockIdx.x * WPB + wave;
    const int nwav  = gridDim.x * WPB;

    float acc_z = 0.f, acc_r = 0.f, acc_d = 0.f;

    int row0 = gwave * 4;
    const int stride = nwav * 4;

    for (; row0 + 3 < n; row0 += stride) {
        const int rowA = row0, rowB = row0 + 1, rowC = row0 + 2, rowD = row0 + 3;
        const int giA = nearest[rowA], giB = nearest[rowB];
        const int giC = nearest[rowC], giD = nearest[rowD];
        const int lbA = gt_lbl[giA], lbB = gt_lbl[giB];
        const int lbC = gt_lbl[giC], lbD = gt_lbl[giD];
        const f32x4* pA = (const f32x4*)(cs + (size_t)rowA * CCOLS);
        const f32x4* pB = (const f32x4*)(cs + (size_t)rowB * CCOLS);
        const f32x4* pC = (const f32x4*)(cs + (size_t)rowC * CCOLS);
        const f32x4* pD = (const f32x4*)(cs + (size_t)rowD * CCOLS);

        // masked row always contains a 0 (zeroed label column) and scores >= 0,
        // so seeding the max at 0 matches the reference exactly.
        float mA = 0.f, mB = 0.f, mC = 0.f, mD = 0.f;
        #pragma unroll
        for (int k = 0; k < 4; ++k) {
            const int   idx   = lane + k * 64;
            const int   cbase = idx * 4;
            const f32x4 vA = __builtin_nontemporal_load(pA + idx);
            const f32x4 vB = __builtin_nontemporal_load(pB + idx);
            const f32x4 vC = __builtin_nontemporal_load(pC + idx);
            const f32x4 vD = __builtin_nontemporal_load(pD + idx);
            const float a0 = (cbase + 0 == lbA) ? 0.f : vA.x;
            const float a1 = (cbase + 1 == lbA) ? 0.f : vA.y;
            const float a2 = (cbase + 2 == lbA) ? 0.f : vA.z;
            const float a3 = (cbase + 3 == lbA) ? 0.f : vA.w;
            const float b0 = (cbase + 0 == lbB) ? 0.f : vB.x;
            const float b1 = (cbase + 1 == lbB) ? 0.f : vB.y;
            const float b2 = (cbase + 2 == lbB) ? 0.f : vB.z;
            const float b3 = (cbase + 3 == lbB) ? 0.f : vB.w;
            const float c0 = (cbase + 0 == lbC) ? 0.f : vC.x;
            const float c1 = (cbase + 1 == lbC) ? 0.f : vC.y;
            const float c2 = (cbase + 2 == lbC) ? 0.f : vC.z;
            const float c3 = (cbase + 3 == lbC) ? 0.f : vC.w;
            const float d0 = (cbase + 0 == lbD) ? 0.f : vD.x;
            const float d1 = (cbase + 1 == lbD) ? 0.f : vD.y;
            const float d2 = (cbase + 2 == lbD) ? 0.f : vD.z;
            const float d3 = (cbase + 3 == lbD) ? 0.f : vD.w;
            mA = fmaxf(mA, fmaxf(fmaxf(a0, a1), fmaxf(a2, a3)));
            mB = fmaxf(mB, fmaxf(fmaxf(b0, b1), fmaxf(b2, b3)));
            mC = fmaxf(mC, fmaxf(fmaxf(c0, c1), fmaxf(c2, c3)));
            mD = fmaxf(mD, fmaxf(fmaxf(d0, d1), fmaxf(d2, d3)));
        }
        // four independent 64-lane max reductions, interleaved
        #pragma unroll
        for (int off = 32; off >= 1; off >>= 1) {
            mA = fmaxf(mA, __shfl_xor(mA, off, 64));
            mB = fmaxf(mB, __shfl_xor(mB, off, 64));
            mC = fmaxf(mC, __shfl_xor(mC, off, 64));
            mD = fmaxf(mD, __shfl_xor(mD, off, 64));
        }

        if (lane == 0) {
            const float lmA = logf(mA), lmB = logf(mB);
            const float lmC = logf(mC), lmD = logf(mD);
            const float zA = z[rowA], zB = z[rowB], zC = z[rowC], zD = z[rowD];
            const float rA = r[rowA], rB = r[rowB], rC = r[rowC], rD = r[rowD];
            const float4 xA = *(const float4*)(xywh    + (size_t)rowA * 4);
            const float4 gA = *(const float4*)(gt_xywh + (size_t)giA  * 4);
            const float4 xB = *(const float4*)(xywh    + (size_t)rowB * 4);
            const float4 gB = *(const float4*)(gt_xywh + (size_t)giB  * 4);
            const float4 xC = *(const float4*)(xywh    + (size_t)rowC * 4);
            const float4 gC = *(const float4*)(gt_xywh + (size_t)giC  * 4);
            const float4 xD = *(const float4*)(xywh    + (size_t)rowD * 4);
            const float4 gD = *(const float4*)(gt_xywh + (size_t)giD  * 4);
            const float dxA = xA.x - gA.x, dyA = xA.y - gA.y,
                        dwA = xA.z - gA.z, dhA = xA.w - gA.w;
            const float dxB = xB.x - gB.x, dyB = xB.y - gB.y,
                        dwB = xB.z - gB.z, dhB = xB.w - gB.w;
            const float dxC = xC.x - gC.x, dyC = xC.y - gC.y,
                        dwC = xC.z - gC.z, dhC = xC.w - gC.w;
            const float dxD = xD.x - gD.x, dyD = xD.y - gD.y,
                        dwD = xD.z - gD.z, dhD = xD.w - gD.w;
            const float distA = dxA*dxA + dyA*dyA + dwA*dwA + dhA*dhA;
            const float distB = dxB*dxB + dyB*dyB + dwB*dwB + dhB*dhB;
            const float distC = dxC*dxC + dyC*dyC + dwC*dwC + dhC*dhC;
            const float distD = dxD*dxD + dyD*dyD + dwD*dwD + dhD*dhD;
            acc_z += zA * lmA + zB * lmB + zC * lmC + zD * lmD;
            acc_r += rA * lmA + rB * lmB + rC * lmC + rD * lmD;
            acc_d += zA * distA + zB * distB + zC * distC + zD * distD;
        }
    }

    // tail: up to 3 remaining rows, one at a time (wave-cooperative)
    for (; row0 < n; ++row0) {
        const int gi = nearest[row0];
        const int lb = gt_lbl[gi];
        const f32x4* p = (const f32x4*)(cs + (size_t)row0 * CCOLS);
        float m = 0.f;
        #pragma unroll
        for (int k = 0; k < 4; ++k) {
            const int idx = lane + k * 64, cbase = idx * 4;
            const f32x4 v = __builtin_nontemporal_load(p + idx);
            const float a = (cbase + 0 == lb) ? 0.f : v.x;
            const float b = (cbase + 1 == lb) ? 0.f : v.y;
            const float c = (cbase + 2 == lb) ? 0.f : v.z;
            const float d = (cbase + 3 == lb) ? 0.f : v.w;
            m = fmaxf(m, fmaxf(fmaxf(a, b), fmaxf(c, d)));
        }
        #pragma unroll
        for (int off = 32; off >= 1; off >>= 1)
            m = fmaxf(m, __shfl_xor(m, off, 64));
        if (lane == 0) {
            const float lm = logf(m);
            const float zi = z[row0], ri = r[row0];
            const float4 x = *(const float4*)(xywh    + (size_t)row0 * 4);
            const float4 g = *(const float4*)(gt_xywh + (size_t)gi   * 4);
            const float dx = x.x - g.x, dy = x.y - g.y,
                        dw = x.z - g.z, dh = x.w - g.w;
            acc_z += zi * lm; acc_r += ri * lm;
            acc_d += zi * (dx*dx + dy*dy + dw*dw + dh*dh);
        }
    }

    __shared__ float s[WPB][3];
    if (lane == 0) { s[wave][0] = acc_z; s[wave][1] = acc_r; s[wave][2] = acc_d; }
    __syncthreads();
    if (threadIdx.x == 0) {
        float sz = 0.f, sr = 0.f, sd = 0.f;
        #pragma unroll
        for (int w = 0; w < WPB; ++w) { sz += s[w][0]; sr += s[w][1]; sd += s[w][2]; }
        partials[            blockIdx.x] = sz;
        partials[    GRID +  blockIdx.x] = sr;
        partials[2 * GRID +  blockIdx.x] = sd;
    }
}

// Final: single block reduces the GRID partials and writes the scalar.
__global__ __launch_bounds__(256) void bp_final(
    const float* __restrict__ partials, float* __restrict__ out)
{
    float sz = 0.f, sr = 0.f, sd = 0.f;
    for (int i = threadIdx.x; i < GRID; i += 256) {
        sz += partials[i];
        sr += partials[GRID + i];
        sd += partials[2 * GRID + i];
    }
    // wave reduce
    #pragma unroll
    for (int off = 32; off >= 1; off >>= 1) {
        sz += __shfl_xor(sz, off, 64);
        sr += __shfl_xor(sr, off, 64);
        sd += __shfl_xor(sd, off, 64);
    }
    __shared__ float sh[4][3];
    const int lane = threadIdx.x & 63;
    const int wave = threadIdx.x >> 6;
    if (lane == 0) { sh[wave][0] = sz; sh[wave][1] = sr; sh[wave][2] = sd; }
    __syncthreads();
    if (threadIdx.x == 0) {
        float tz = 0.f, tr = 0.f, td = 0.f;
        #pragma unroll
        for (int w = 0; w < 4; ++w) { tz += sh[w][0]; tr += sh[w][1]; td += sh[w][2]; }
        // tpc + tps + fpc = -tz + exp(-td) - tr
        out[0] = -tz - tr + expf(-td);
    }
}

extern "C" void kernel_launch(void* const* d_in, const int* in_sizes, int n_in,
                              void* d_out, int out_size, void* d_ws, size_t ws_size,
                              hipStream_t stream) {
    const float* cs      = (const float*)d_in[0];
    const float* xywh    = (const float*)d_in[1];
    const float* z       = (const float*)d_in[2];
    const float* r       = (const float*)d_in[3];
    const int*   nearest = (const int*)  d_in[4];
    const int*   gt_lbl  = (const int*)  d_in[5];
    const float* gt_xywh = (const float*)d_in[6];
    float* out = (float*)d_out;
    float* partials = (float*)d_ws;     // needs 3*GRID*4 = 12 KB
    const int n = in_sizes[2];          // N (z has N elements)

    bp_main<<<GRID, BLOCK, 0, stream>>>(cs, xywh, z, r, nearest, gt_lbl,
                                        gt_xywh, partials, n);
    bp_final<<<1, 256, 0, stream>>>(partials, out);
}

// Round 11
// 67.746 us; speedup vs baseline: 1.0162x; 1.0162x over previous
//
#include <hip/hip_runtime.h>
#include <math.h>

#define NROWS 100000
#define CCOLS 1024
#define GRID  1024
#define BLOCK 256
#define WPB   (BLOCK / 64)   // waves per block

typedef float f32x4 __attribute__((ext_vector_type(4)));  // native vector for nontemporal builtin

// One wave per ROW-PAIR, grid-stride. 8 nt-loads in flight per iteration; the
// two 64-lane reduce chains interleave (independent), halving the per-row
// pipeline bubble vs the 1-row version. Epilogue stays lane0-serial (cheap).
// Best measured config (R9: 68.2 us, ~6.05 TB/s end-to-end):
//   - NT loads on the 410 MB single-use stream (R8: -3.2 us vs cached)
//   - 2-row ILP (R9: -4.1 us); 4-row regressed (R10), GRID=2048 regressed (R5),
//     threadfence fusion regressed hard (R6).
__global__ __launch_bounds__(BLOCK) void bp_main(
    const float* __restrict__ cs,        // [N, C] class_scores
    const float* __restrict__ xywh,      // [N, 4]
    const float* __restrict__ z,         // [N]
    const float* __restrict__ r,         // [N]
    const int*   __restrict__ nearest,   // [N]
    const int*   __restrict__ gt_lbl,    // [M]
    const float* __restrict__ gt_xywh,   // [M, 4]
    float* __restrict__ partials,        // [3 * GRID]
    int n)
{
    const int lane  = threadIdx.x & 63;
    const int wave  = threadIdx.x >> 6;
    const int gwave = blockIdx.x * WPB + wave;
    const int nwav  = gridDim.x * WPB;

    float acc_z = 0.f, acc_r = 0.f, acc_d = 0.f;

    int row0 = gwave * 2;
    const int stride = nwav * 2;

    for (; row0 + 1 < n; row0 += stride) {
        const int rowA = row0, rowB = row0 + 1;
        const int giA = nearest[rowA], giB = nearest[rowB];
        const int lbA = gt_lbl[giA],   lbB = gt_lbl[giB];
        const f32x4* pA = (const f32x4*)(cs + (size_t)rowA * CCOLS);
        const f32x4* pB = (const f32x4*)(cs + (size_t)rowB * CCOLS);

        // masked row always contains a 0 (zeroed label column) and scores >= 0,
        // so seeding the max at 0 matches the reference exactly.
        float mA = 0.f, mB = 0.f;
        #pragma unroll
        for (int k = 0; k < 4; ++k) {
            const int   idx   = lane + k * 64;
            const int   cbase = idx * 4;
            const f32x4 vA = __builtin_nontemporal_load(pA + idx);
            const f32x4 vB = __builtin_nontemporal_load(pB + idx);
            const float a0 = (cbase + 0 == lbA) ? 0.f : vA.x;
            const float a1 = (cbase + 1 == lbA) ? 0.f : vA.y;
            const float a2 = (cbase + 2 == lbA) ? 0.f : vA.z;
            const float a3 = (cbase + 3 == lbA) ? 0.f : vA.w;
            const float b0 = (cbase + 0 == lbB) ? 0.f : vB.x;
            const float b1 = (cbase + 1 == lbB) ? 0.f : vB.y;
            const float b2 = (cbase + 2 == lbB) ? 0.f : vB.z;
            const float b3 = (cbase + 3 == lbB) ? 0.f : vB.w;
            mA = fmaxf(mA, fmaxf(fmaxf(a0, a1), fmaxf(a2, a3)));
            mB = fmaxf(mB, fmaxf(fmaxf(b0, b1), fmaxf(b2, b3)));
        }
        // two independent 64-lane max reductions, interleaved
        #pragma unroll
        for (int off = 32; off >= 1; off >>= 1) {
            mA = fmaxf(mA, __shfl_xor(mA, off, 64));
            mB = fmaxf(mB, __shfl_xor(mB, off, 64));
        }

        if (lane == 0) {
            const float lmA = logf(mA);
            const float lmB = logf(mB);
            const float zA = z[rowA], zB = z[rowB];
            const float rA = r[rowA], rB = r[rowB];
            const float4 xA = *(const float4*)(xywh    + (size_t)rowA * 4);
            const float4 gA = *(const float4*)(gt_xywh + (size_t)giA  * 4);
            const float4 xB = *(const float4*)(xywh    + (size_t)rowB * 4);
            const float4 gB = *(const float4*)(gt_xywh + (size_t)giB  * 4);
            const float dxA = xA.x - gA.x, dyA = xA.y - gA.y,
                        dwA = xA.z - gA.z, dhA = xA.w - gA.w;
            const float dxB = xB.x - gB.x, dyB = xB.y - gB.y,
                        dwB = xB.z - gB.z, dhB = xB.w - gB.w;
            const float distA = dxA*dxA + dyA*dyA + dwA*dwA + dhA*dhA;
            const float distB = dxB*dxB + dyB*dyB + dwB*dwB + dhB*dhB;
            acc_z += zA * lmA + zB * lmB;
            acc_r += rA * lmA + rB * lmB;
            acc_d += zA * distA + zB * distB;
        }
    }

    // odd-N tail (not hit for N=100000, kept for generality)
    if (row0 < n) {
        const int gi = nearest[row0];
        const int lb = gt_lbl[gi];
        const f32x4* p = (const f32x4*)(cs + (size_t)row0 * CCOLS);
        float m = 0.f;
        #pragma unroll
        for (int k = 0; k < 4; ++k) {
            const int idx = lane + k * 64, cbase = idx * 4;
            const f32x4 v = __builtin_nontemporal_load(p + idx);
            const float a = (cbase + 0 == lb) ? 0.f : v.x;
            const float b = (cbase + 1 == lb) ? 0.f : v.y;
            const float c = (cbase + 2 == lb) ? 0.f : v.z;
            const float d = (cbase + 3 == lb) ? 0.f : v.w;
            m = fmaxf(m, fmaxf(fmaxf(a, b), fmaxf(c, d)));
        }
        #pragma unroll
        for (int off = 32; off >= 1; off >>= 1)
            m = fmaxf(m, __shfl_xor(m, off, 64));
        if (lane == 0) {
            const float lm = logf(m);
            const float zi = z[row0], ri = r[row0];
            const float4 x = *(const float4*)(xywh    + (size_t)row0 * 4);
            const float4 g = *(const float4*)(gt_xywh + (size_t)gi   * 4);
            const float dx = x.x - g.x, dy = x.y - g.y,
                        dw = x.z - g.z, dh = x.w - g.w;
            acc_z += zi * lm; acc_r += ri * lm;
            acc_d += zi * (dx*dx + dy*dy + dw*dw + dh*dh);
        }
    }

    __shared__ float s[WPB][3];
    if (lane == 0) { s[wave][0] = acc_z; s[wave][1] = acc_r; s[wave][2] = acc_d; }
    __syncthreads();
    if (threadIdx.x == 0) {
        float sz = 0.f, sr = 0.f, sd = 0.f;
        #pragma unroll
        for (int w = 0; w < WPB; ++w) { sz += s[w][0]; sr += s[w][1]; sd += s[w][2]; }
        partials[            blockIdx.x] = sz;
        partials[    GRID +  blockIdx.x] = sr;
        partials[2 * GRID +  blockIdx.x] = sd;
    }
}

// Final: single block reduces the GRID partials and writes the scalar.
__global__ __launch_bounds__(256) void bp_final(
    const float* __restrict__ partials, float* __restrict__ out)
{
    float sz = 0.f, sr = 0.f, sd = 0.f;
    for (int i = threadIdx.x; i < GRID; i += 256) {
        sz += partials[i];
        sr += partials[GRID + i];
        sd += partials[2 * GRID + i];
    }
    // wave reduce
    #pragma unroll
    for (int off = 32; off >= 1; off >>= 1) {
        sz += __shfl_xor(sz, off, 64);
        sr += __shfl_xor(sr, off, 64);
        sd += __shfl_xor(sd, off, 64);
    }
    __shared__ float sh[4][3];
    const int lane = threadIdx.x & 63;
    const int wave = threadIdx.x >> 6;
    if (lane == 0) { sh[wave][0] = sz; sh[wave][1] = sr; sh[wave][2] = sd; }
    __syncthreads();
    if (threadIdx.x == 0) {
        float tz = 0.f, tr = 0.f, td = 0.f;
        #pragma unroll
        for (int w = 0; w < 4; ++w) { tz += sh[w][0]; tr += sh[w][1]; td += sh[w][2]; }
        // tpc + tps + fpc = -tz + exp(-td) - tr
        out[0] = -tz - tr + expf(-td);
    }
}

extern "C" void kernel_launch(void* const* d_in, const int* in_sizes, int n_in,
                              void* d_out, int out_size, void* d_ws, size_t ws_size,
                              hipStream_t stream) {
    const float* cs      = (const float*)d_in[0];
    const float* xywh    = (const float*)d_in[1];
    const float* z       = (const float*)d_in[2];
    const float* r       = (const float*)d_in[3];
    const int*   nearest = (const int*)  d_in[4];
    const int*   gt_lbl  = (const int*)  d_in[5];
    const float* gt_xywh = (const float*)d_in[6];
    float* out = (float*)d_out;
    float* partials = (float*)d_ws;     // needs 3*GRID*4 = 12 KB
    const int n = in_sizes[2];          // N (z has N elements)

    bp_main<<<GRID, BLOCK, 0, stream>>>(cs, xywh, z, r, nearest, gt_lbl,
                                        gt_xywh, partials, n);
    bp_final<<<1, 256, 0, stream>>>(partials, out);
}